// Round 1
// baseline (263.098 us; speedup 1.0000x reference)
//
#include <hip/hip_runtime.h>
#include <math.h>

#define DD 256
#define MM 2048
#define NN 512

// K1: blocks 0..255:   B1[d][j]  = (1/16) * sum_a wq[a][d]*wk[a][j]
//     blocks 256..511: B2T[d][j] = sum_e wo[j][e]*wv[e][d]   (= (wo@wv).T)
__global__ void prep_weights(const float* __restrict__ wq, const float* __restrict__ wk,
                             const float* __restrict__ wv, const float* __restrict__ wo,
                             float* __restrict__ B1, float* __restrict__ B2T) {
    __shared__ float sA[DD];
    const int j = threadIdx.x;
    const int b = blockIdx.x;
    if (b < DD) {
        const int d = b;
        sA[j] = wq[j * DD + d];            // column d of wq
        __syncthreads();
        float acc = 0.f;
        for (int a = 0; a < DD; ++a) acc += sA[a] * wk[a * DD + j];
        B1[d * DD + j] = acc * 0.0625f;    // fold 1/sqrt(256)
    } else {
        const int d = b - DD;
        sA[j] = wv[j * DD + d];            // column d of wv
        __syncthreads();
        float acc = 0.f;
        for (int e = 0; e < DD; ++e) acc += wo[j * DD + e] * sA[e];
        B2T[d * DD + j] = acc;
    }
}

// Y[m][j] = sum_d X[m][d] * W[d*DD + j], ROWS rows of X per block, 256 threads.
template <int ROWS>
__global__ void rowgemm(const float* __restrict__ X, const float* __restrict__ W,
                        float* __restrict__ Y) {
    __shared__ float sX[ROWS][DD];
    const int j = threadIdx.x;
    const int m0 = blockIdx.x * ROWS;
    for (int r = 0; r < ROWS; ++r) sX[r][j] = X[(size_t)(m0 + r) * DD + j];
    __syncthreads();
    float acc[ROWS];
#pragma unroll
    for (int r = 0; r < ROWS; ++r) acc[r] = 0.f;
    for (int d = 0; d < DD; ++d) {
        const float w = W[d * DD + j];
#pragma unroll
        for (int r = 0; r < ROWS; ++r) acc[r] += sX[r][d] * w;
    }
    for (int r = 0; r < ROWS; ++r) Y[(size_t)(m0 + r) * DD + j] = acc[r];
}

// Main fused kernel: one block per m, 4 waves, each wave streams n = wave, wave+4, ...
// kv read ONCE; logits kept in LDS; online softmax accumulates c in registers.
__global__ __launch_bounds__(256, 8)
void attn_main(const float* __restrict__ kv, const float* __restrict__ qt,
               float* __restrict__ c_out, float* __restrict__ attn_out) {
    __shared__ float s_logits[NN];
    __shared__ float s_wmax[4], s_wl[4];
    __shared__ float s_wc[4][DD];

    const int m = blockIdx.x;
    const int tid = threadIdx.x;
    const int wave = tid >> 6;
    const int lane = tid & 63;

    // each lane holds qt[m][lane*4 .. lane*4+3]
    const float4 qv = ((const float4*)(qt + (size_t)m * DD))[lane];
    const float4* kv4 = (const float4*)(kv + (size_t)m * NN * DD);

    float mw = -1e30f, lw = 0.f;
    float4 c4 = make_float4(0.f, 0.f, 0.f, 0.f);

    for (int n = wave; n < NN; n += 4) {
        const float4 kvv = kv4[(size_t)n * 64 + lane];            // 1 KB/wave, coalesced
        float p = kvv.x * qv.x + kvv.y * qv.y + kvv.z * qv.z + kvv.w * qv.w;
#pragma unroll
        for (int off = 32; off > 0; off >>= 1)                    // butterfly: all lanes get sum
            p += __shfl_xor(p, off, 64);
        const float logit = p;
        if (lane == 0) s_logits[n] = logit;
        if (logit > mw) {                                         // rescale path (rare)
            const float sc = __expf(mw - logit);
            lw = lw * sc + 1.f;
            c4.x = c4.x * sc + kvv.x;
            c4.y = c4.y * sc + kvv.y;
            c4.z = c4.z * sc + kvv.z;
            c4.w = c4.w * sc + kvv.w;
            mw = logit;
        } else {
            const float pe = __expf(logit - mw);
            lw += pe;
            c4.x += pe * kvv.x;
            c4.y += pe * kvv.y;
            c4.z += pe * kvv.z;
            c4.w += pe * kvv.w;
        }
    }

    if (lane == 0) { s_wmax[wave] = mw; s_wl[wave] = lw; }
    s_wc[wave][lane * 4 + 0] = c4.x;
    s_wc[wave][lane * 4 + 1] = c4.y;
    s_wc[wave][lane * 4 + 2] = c4.z;
    s_wc[wave][lane * 4 + 3] = c4.w;
    __syncthreads();

    const float Mg = fmaxf(fmaxf(s_wmax[0], s_wmax[1]), fmaxf(s_wmax[2], s_wmax[3]));
    const float ew0 = __expf(s_wmax[0] - Mg), ew1 = __expf(s_wmax[1] - Mg);
    const float ew2 = __expf(s_wmax[2] - Mg), ew3 = __expf(s_wmax[3] - Mg);
    const float L = s_wl[0] * ew0 + s_wl[1] * ew1 + s_wl[2] * ew2 + s_wl[3] * ew3;
    const float invL = 1.f / L;

    // c[m][tid] = (sum over waves of partial c, rescaled) / L
    const float cd = s_wc[0][tid] * ew0 + s_wc[1][tid] * ew1 +
                     s_wc[2][tid] * ew2 + s_wc[3][tid] * ew3;
    c_out[(size_t)m * DD + tid] = cd * invL;

    // attn[m][n] = exp(logit - Mg) / L
    attn_out[(size_t)m * NN + tid]       = __expf(s_logits[tid] - Mg) * invL;
    attn_out[(size_t)m * NN + tid + 256] = __expf(s_logits[tid + 256] - Mg) * invL;
}

extern "C" void kernel_launch(void* const* d_in, const int* in_sizes, int n_in,
                              void* d_out, int out_size, void* d_ws, size_t ws_size,
                              hipStream_t stream) {
    const float* q_vec = (const float*)d_in[0];
    const float* kv    = (const float*)d_in[1];
    const float* wq    = (const float*)d_in[2];
    const float* wk    = (const float*)d_in[3];
    const float* wv    = (const float*)d_in[4];
    const float* wo    = (const float*)d_in[5];

    float* out  = (float*)d_out;                     // [M, D], first in tuple
    float* attn = (float*)d_out + (size_t)MM * DD;   // [M, N], second in tuple

    float* B1  = (float*)d_ws;                       // [D, D] (scaled by 1/16)
    float* B2T = B1 + DD * DD;                       // [D, D] = (wo@wv).T
    float* qt  = B2T + DD * DD;                      // [M, D]
    float* cws = qt + (size_t)MM * DD;               // [M, D]

    prep_weights<<<2 * DD, DD, 0, stream>>>(wq, wk, wv, wo, B1, B2T);
    rowgemm<16><<<MM / 16, DD, 0, stream>>>(q_vec, B1, qt);     // qt = q_vec @ B1
    attn_main<<<MM, DD, 0, stream>>>(kv, qt, cws, attn);
    rowgemm<16><<<MM / 16, DD, 0, stream>>>(cws, B2T, out);     // out = c @ B2T
}

// Round 2
// 242.016 us; speedup vs baseline: 1.0871x; 1.0871x over previous
//
#include <hip/hip_runtime.h>
#include <math.h>

#define DD 256
#define MM 2048
#define NN 512

// blocks 0..255:   B1[d][j]  = (1/16) * sum_a wq[a][d]*wk[a][j]   (qt = q_vec @ B1)
// blocks 256..511: B2T[d][j] = sum_e wo[j][e]*wv[e][d]            (out = c @ B2T)
__global__ void prep_weights(const float* __restrict__ wq, const float* __restrict__ wk,
                             const float* __restrict__ wv, const float* __restrict__ wo,
                             float* __restrict__ B1, float* __restrict__ B2T) {
    __shared__ float sA[DD];
    const int j = threadIdx.x;
    const int b = blockIdx.x;
    if (b < DD) {
        const int d = b;
        sA[j] = wq[j * DD + d];            // column d of wq
        __syncthreads();
        float acc = 0.f;
        for (int a = 0; a < DD; ++a) acc = fmaf(sA[a], wk[a * DD + j], acc);
        B1[d * DD + j] = acc * 0.0625f;    // fold 1/sqrt(256)
    } else {
        const int d = b - DD;
        sA[j] = wv[j * DD + d];            // column d of wv
        __syncthreads();
        float acc = 0.f;
        for (int e = 0; e < DD; ++e) acc = fmaf(wo[j * DD + e], sA[e], acc);
        B2T[d * DD + j] = acc;
    }
}

// One block per m. 4 waves; each wave handles 4 n-rows per iteration with
// 16 lanes per row (each lane owns 4x float4 of the d-range). Reduce = 4
// shfl_xor within the 16-lane group; every lane ends with its row's logit,
// so pe*kv accumulation is register-local. No online max (|logit| <~ 3).
// Fused: qt = q_vec@B1 prologue, out = c@B2T epilogue (B1/B2T L2-resident).
__global__ __launch_bounds__(256, 4)
void attn_fused(const float* __restrict__ q_vec, const float* __restrict__ kv,
                const float* __restrict__ B1, const float* __restrict__ B2T,
                float* __restrict__ out, float* __restrict__ attn_out) {
    __shared__ float s_pe[NN];          // exp(logit[n])
    __shared__ float s_lw[16];          // per-(wave,grp) sum of pe
    __shared__ float s_wc[16][DD];      // per-(wave,grp) partial c (16 KB)
    __shared__ float s_q[DD];           // q_vec row, later reused for c
    __shared__ float s_qt[DD];          // qt row

    const int m    = blockIdx.x;
    const int tid  = threadIdx.x;
    const int wave = tid >> 6;
    const int lane = tid & 63;
    const int grp  = lane >> 4;
    const int l16  = lane & 15;

    // ---- prologue: qt[m] = q_vec[m] @ B1 ----
    s_q[tid] = q_vec[(size_t)m * DD + tid];
    __syncthreads();
    {
        float a = 0.f;
#pragma unroll 8
        for (int d = 0; d < DD; ++d) a = fmaf(s_q[d], B1[d * DD + tid], a);
        s_qt[tid] = a;
    }
    __syncthreads();

    const float4* qt4 = (const float4*)s_qt;
    const float4 qv0 = qt4[l16];
    const float4 qv1 = qt4[l16 + 16];
    const float4 qv2 = qt4[l16 + 32];
    const float4 qv3 = qt4[l16 + 48];

    const float4* kv4 = (const float4*)(kv + (size_t)m * NN * DD);
    float4 c0 = make_float4(0.f, 0.f, 0.f, 0.f);
    float4 c1 = c0, c2 = c0, c3 = c0;
    float lw = 0.f;
    const int nbase = wave * 4 + grp;

#pragma unroll 2
    for (int it = 0; it < NN / 16; ++it) {
        const int n = it * 16 + nbase;
        const float4* row = kv4 + (size_t)n * (DD / 4);
        const float4 k0 = row[l16];
        const float4 k1 = row[l16 + 16];
        const float4 k2 = row[l16 + 32];
        const float4 k3 = row[l16 + 48];

        float p;
        p = k0.x * qv0.x;
        p = fmaf(k0.y, qv0.y, p); p = fmaf(k0.z, qv0.z, p); p = fmaf(k0.w, qv0.w, p);
        p = fmaf(k1.x, qv1.x, p); p = fmaf(k1.y, qv1.y, p);
        p = fmaf(k1.z, qv1.z, p); p = fmaf(k1.w, qv1.w, p);
        p = fmaf(k2.x, qv2.x, p); p = fmaf(k2.y, qv2.y, p);
        p = fmaf(k2.z, qv2.z, p); p = fmaf(k2.w, qv2.w, p);
        p = fmaf(k3.x, qv3.x, p); p = fmaf(k3.y, qv3.y, p);
        p = fmaf(k3.z, qv3.z, p); p = fmaf(k3.w, qv3.w, p);

        p += __shfl_xor(p, 1);
        p += __shfl_xor(p, 2);
        p += __shfl_xor(p, 4);
        p += __shfl_xor(p, 8);

        const float pe = __expf(p);
        if (l16 == 0) s_pe[n] = pe;
        lw += pe;

        c0.x = fmaf(pe, k0.x, c0.x); c0.y = fmaf(pe, k0.y, c0.y);
        c0.z = fmaf(pe, k0.z, c0.z); c0.w = fmaf(pe, k0.w, c0.w);
        c1.x = fmaf(pe, k1.x, c1.x); c1.y = fmaf(pe, k1.y, c1.y);
        c1.z = fmaf(pe, k1.z, c1.z); c1.w = fmaf(pe, k1.w, c1.w);
        c2.x = fmaf(pe, k2.x, c2.x); c2.y = fmaf(pe, k2.y, c2.y);
        c2.z = fmaf(pe, k2.z, c2.z); c2.w = fmaf(pe, k2.w, c2.w);
        c3.x = fmaf(pe, k3.x, c3.x); c3.y = fmaf(pe, k3.y, c3.y);
        c3.z = fmaf(pe, k3.z, c3.z); c3.w = fmaf(pe, k3.w, c3.w);
    }

    const int pidx = wave * 4 + grp;
    if (l16 == 0) s_lw[pidx] = lw;
    float4* wc4 = (float4*)(&s_wc[pidx][0]);
    wc4[l16]      = c0;
    wc4[l16 + 16] = c1;
    wc4[l16 + 32] = c2;
    wc4[l16 + 48] = c3;
    __syncthreads();

    float L = 0.f;
#pragma unroll
    for (int i = 0; i < 16; ++i) L += s_lw[i];
    const float invL = 1.f / L;

    float cd = 0.f;
#pragma unroll
    for (int i = 0; i < 16; ++i) cd += s_wc[i][tid];
    cd *= invL;
    __syncthreads();
    s_q[tid] = cd;                       // reuse s_q as normalized c row
    __syncthreads();

    attn_out[(size_t)m * NN + tid]       = s_pe[tid] * invL;
    attn_out[(size_t)m * NN + tid + 256] = s_pe[tid + 256] * invL;

    // ---- epilogue: out[m] = c @ B2T ----
    float o = 0.f;
#pragma unroll 8
    for (int d = 0; d < DD; ++d) o = fmaf(s_q[d], B2T[d * DD + tid], o);
    out[(size_t)m * DD + tid] = o;
}

extern "C" void kernel_launch(void* const* d_in, const int* in_sizes, int n_in,
                              void* d_out, int out_size, void* d_ws, size_t ws_size,
                              hipStream_t stream) {
    const float* q_vec = (const float*)d_in[0];
    const float* kv    = (const float*)d_in[1];
    const float* wq    = (const float*)d_in[2];
    const float* wk    = (const float*)d_in[3];
    const float* wv    = (const float*)d_in[4];
    const float* wo    = (const float*)d_in[5];

    float* out  = (float*)d_out;                     // [M, D]
    float* attn = (float*)d_out + (size_t)MM * DD;   // [M, N]

    float* B1  = (float*)d_ws;                       // [D, D] (scaled by 1/16)
    float* B2T = B1 + DD * DD;                       // [D, D] = (wo@wv).T

    prep_weights<<<2 * DD, DD, 0, stream>>>(wq, wk, wv, wo, B1, B2T);
    attn_fused<<<MM, DD, 0, stream>>>(q_vec, kv, B1, B2T, out, attn);
}

// Round 3
// 208.759 us; speedup vs baseline: 1.2603x; 1.1593x over previous
//
#include <hip/hip_runtime.h>
#include <math.h>

#define DD 256
#define MM 2048
#define NN 512

typedef float f32x4 __attribute__((ext_vector_type(4)));

__device__ inline f32x4 ld_nt(const f32x4* p) {
    return __builtin_nontemporal_load(p);
}

// blocks 0..255:   B1[d][j]  = (1/16) * sum_a wq[a][d]*wk[a][j]   (qt = q_vec @ B1)
// blocks 256..511: B2T[d][j] = sum_e wo[j][e]*wv[e][d]            (out = c @ B2T)
__global__ void prep_weights(const float* __restrict__ wq, const float* __restrict__ wk,
                             const float* __restrict__ wv, const float* __restrict__ wo,
                             float* __restrict__ B1, float* __restrict__ B2T) {
    __shared__ float sA[DD];
    const int j = threadIdx.x;
    const int b = blockIdx.x;
    if (b < DD) {
        const int d = b;
        sA[j] = wq[j * DD + d];
        __syncthreads();
        float acc = 0.f;
        for (int a = 0; a < DD; ++a) acc = fmaf(sA[a], wk[a * DD + j], acc);
        B1[d * DD + j] = acc * 0.0625f;
    } else {
        const int d = b - DD;
        sA[j] = wv[j * DD + d];
        __syncthreads();
        float acc = 0.f;
        for (int e = 0; e < DD; ++e) acc = fmaf(wo[j * DD + e], sA[e], acc);
        B2T[d * DD + j] = acc;
    }
}

// One block per m; 4 waves; 16 lanes per n-row (4 rows/wave/iter).
// Explicit register double-buffer on kv tiles; nontemporal kv loads;
// wave-internal shfl reduce of partial c (LDS 8.4 KB -> 8 blocks/CU).
__global__ __launch_bounds__(256, 4)
void attn_fused(const float* __restrict__ q_vec, const float* __restrict__ kv,
                const float* __restrict__ B1, const float* __restrict__ B2T,
                float* __restrict__ out, float* __restrict__ attn_out) {
    __shared__ float s_pe[NN];
    __shared__ float s_lw[4];
    __shared__ float s_wc[4][DD];
    __shared__ float s_q[DD];
    __shared__ float s_qt[DD];

    const int m    = blockIdx.x;
    const int tid  = threadIdx.x;
    const int wave = tid >> 6;
    const int lane = tid & 63;
    const int grp  = lane >> 4;
    const int l16  = lane & 15;

    // ---- prologue: qt[m] = q_vec[m] @ B1 ----
    s_q[tid] = q_vec[(size_t)m * DD + tid];
    __syncthreads();
    {
        float a = 0.f;
#pragma unroll 8
        for (int d = 0; d < DD; ++d) a = fmaf(s_q[d], B1[d * DD + tid], a);
        s_qt[tid] = a;
    }
    __syncthreads();

    const f32x4* qt4 = (const f32x4*)s_qt;
    const f32x4 qv0 = qt4[l16];
    const f32x4 qv1 = qt4[l16 + 16];
    const f32x4 qv2 = qt4[l16 + 32];
    const f32x4 qv3 = qt4[l16 + 48];

    const int nbase = wave * 4 + grp;
    // lane's pointer into its first row (it = 0): row nbase, float4 index l16
    const f32x4* p = (const f32x4*)(kv + (size_t)m * NN * DD) + (size_t)nbase * 64 + l16;
    const int STRIDE = 16 * 64;   // 16 rows per iteration, in float4 units

    f32x4 c0 = (f32x4)0.f, c1 = (f32x4)0.f, c2 = (f32x4)0.f, c3 = (f32x4)0.f;
    float lw = 0.f;

    f32x4 a0 = ld_nt(p), a1 = ld_nt(p + 16), a2 = ld_nt(p + 32), a3 = ld_nt(p + 48);

#pragma unroll 2
    for (int it = 0; it < NN / 16; ++it) {
        f32x4 b0, b1, b2, b3;
        if (it + 1 < NN / 16) {
            const f32x4* np = p + (size_t)(it + 1) * STRIDE;
            b0 = ld_nt(np); b1 = ld_nt(np + 16); b2 = ld_nt(np + 32); b3 = ld_nt(np + 48);
        }
        // dot(qt, kv_row) for this group's row
        f32x4 t = a0 * qv0 + a1 * qv1 + a2 * qv2 + a3 * qv3;
        float pdot = (t[0] + t[1]) + (t[2] + t[3]);
        pdot += __shfl_xor(pdot, 1);
        pdot += __shfl_xor(pdot, 2);
        pdot += __shfl_xor(pdot, 4);
        pdot += __shfl_xor(pdot, 8);

        const float pe = __expf(pdot);
        if (l16 == 0) s_pe[it * 16 + nbase] = pe;
        lw += pe;

        c0 += pe * a0;
        c1 += pe * a1;
        c2 += pe * a2;
        c3 += pe * a3;

        a0 = b0; a1 = b1; a2 = b2; a3 = b3;
    }

    // ---- wave-internal reduce across the 4 groups (lanes ^16, ^32) ----
#pragma unroll
    for (int i = 0; i < 4; ++i) {
        c0[i] += __shfl_xor(c0[i], 16); c1[i] += __shfl_xor(c1[i], 16);
        c2[i] += __shfl_xor(c2[i], 16); c3[i] += __shfl_xor(c3[i], 16);
        c0[i] += __shfl_xor(c0[i], 32); c1[i] += __shfl_xor(c1[i], 32);
        c2[i] += __shfl_xor(c2[i], 32); c3[i] += __shfl_xor(c3[i], 32);
    }
    lw += __shfl_xor(lw, 16);
    lw += __shfl_xor(lw, 32);

    // all lanes now hold the wave's full partial c (c0..c3 identical across groups);
    // group g writes quadrant g
    {
        f32x4* wc4 = (f32x4*)(&s_wc[wave][0]);
        const f32x4 cg = (grp == 0) ? c0 : (grp == 1) ? c1 : (grp == 2) ? c2 : c3;
        wc4[grp * 16 + l16] = cg;
        if (lane == 0) s_lw[wave] = lw;
    }
    __syncthreads();

    const float L = s_lw[0] + s_lw[1] + s_lw[2] + s_lw[3];
    const float invL = 1.f / L;

    float cd = (s_wc[0][tid] + s_wc[1][tid]) + (s_wc[2][tid] + s_wc[3][tid]);
    cd *= invL;
    __syncthreads();
    s_q[tid] = cd;                       // reuse s_q as normalized c row
    __syncthreads();

    attn_out[(size_t)m * NN + tid]       = s_pe[tid] * invL;
    attn_out[(size_t)m * NN + tid + 256] = s_pe[tid + 256] * invL;

    // ---- epilogue: out[m] = c @ B2T ----
    float o = 0.f;
#pragma unroll 8
    for (int d = 0; d < DD; ++d) o = fmaf(s_q[d], B2T[d * DD + tid], o);
    out[(size_t)m * DD + tid] = o;
}

extern "C" void kernel_launch(void* const* d_in, const int* in_sizes, int n_in,
                              void* d_out, int out_size, void* d_ws, size_t ws_size,
                              hipStream_t stream) {
    const float* q_vec = (const float*)d_in[0];
    const float* kv    = (const float*)d_in[1];
    const float* wq    = (const float*)d_in[2];
    const float* wk    = (const float*)d_in[3];
    const float* wv    = (const float*)d_in[4];
    const float* wo    = (const float*)d_in[5];

    float* out  = (float*)d_out;                     // [M, D]
    float* attn = (float*)d_out + (size_t)MM * DD;   // [M, N]

    float* B1  = (float*)d_ws;                       // [D, D] (scaled by 1/16)
    float* B2T = B1 + DD * DD;                       // [D, D] = (wo@wv).T

    prep_weights<<<2 * DD, DD, 0, stream>>>(wq, wk, wv, wo, B1, B2T);
    attn_fused<<<MM, DD, 0, stream>>>(q_vec, kv, B1, B2T, out, attn);
}